// Round 1
// baseline (2277.055 us; speedup 1.0000x reference)
//
#include <hip/hip_runtime.h>
#include <cstdint>
#include <cstddef>

typedef unsigned short u16;
typedef short bf16x8 __attribute__((ext_vector_type(8)));
typedef float f32x4 __attribute__((ext_vector_type(4)));

#define S_LEN 4096
#define HID   2304
#define NH    8
#define NKV   4
#define HD    256
#define QD    2048   // NH*HD
#define KD    1024   // NKV*HD
#define QKVW  4096   // QD + KD + KD

__device__ __forceinline__ u16 f2b(float f) {
    union { float f; uint32_t u; } v; v.f = f;
    uint32_t r = (v.u + 0x7FFFu + ((v.u >> 16) & 1u)) >> 16;
    return (u16)r;
}
__device__ __forceinline__ float b2f(u16 u) {
    union { uint32_t u; float f; } v; v.u = ((uint32_t)u) << 16;
    return v.f;
}

// ---------------- fp32 -> bf16 convert (hidden states) ----------------
__global__ __launch_bounds__(256) void cvt_h(const float* __restrict__ in, u16* __restrict__ out, int n4) {
    int id = blockIdx.x * 256 + threadIdx.x;
    if (id >= n4) return;
    float4 v = ((const float4*)in)[id];
    uint2 o;
    o.x = (uint32_t)f2b(v.x) | ((uint32_t)f2b(v.y) << 16);
    o.y = (uint32_t)f2b(v.z) | ((uint32_t)f2b(v.w) << 16);
    ((uint2*)out)[id] = o;
}

// ---------------- weight transpose+convert: W[K][N] f32 -> out[n][k] bf16 ----------------
__global__ __launch_bounds__(256) void twcvt(const float* __restrict__ W, u16* __restrict__ out,
                                             int K, int N, int ldo) {
    const int n0 = blockIdx.x * 64, k0 = blockIdx.y * 64;
    __shared__ float T[64][68];
    const int t = threadIdx.x;
    for (int i = 0; i < 4; i++) {
        int id = i * 256 + t;
        int r = id >> 4, c4 = id & 15;
        float4 v = *(const float4*)(W + (size_t)(k0 + r) * N + n0 + c4 * 4);
        *(float4*)(&T[r][c4 * 4]) = v;
    }
    __syncthreads();
    for (int i = 0; i < 4; i++) {
        int id = i * 256 + t;
        int rn = id >> 4, c4 = id & 15;
        u16 a = f2b(T[c4 * 4 + 0][rn]);
        u16 b = f2b(T[c4 * 4 + 1][rn]);
        u16 c = f2b(T[c4 * 4 + 2][rn]);
        u16 d = f2b(T[c4 * 4 + 3][rn]);
        uint2 o;
        o.x = (uint32_t)a | ((uint32_t)b << 16);
        o.y = (uint32_t)c | ((uint32_t)d << 16);
        *(uint2*)(out + (size_t)(n0 + rn) * ldo + k0 + c4 * 4) = o;
    }
}

// ---------------- GEMM: C[M][N] = A[M][K] * B[N][K]^T, bf16 in, f32 acc ----------------
// 128x128 block tile, BK=32, 4 waves (2x2 of 64x64), XOR-swizzled LDS (16B aligned b128).
__global__ __launch_bounds__(256) void gemm_bt(const u16* __restrict__ A, const u16* __restrict__ B,
                                               void* __restrict__ Cp, int M, int N, int K, int bf16_out) {
    const int tid  = threadIdx.x;
    const int wave = tid >> 6, lane = tid & 63;
    const int quad = lane >> 4, m16 = lane & 15;
    const int m0 = blockIdx.y * 128, n0 = blockIdx.x * 128;
    const int wm = (wave & 1) * 64, wn = (wave >> 1) * 64;
    __shared__ u16 As[128 * 32];
    __shared__ u16 Bs[128 * 32];
    const f32x4 zero4 = {0.f, 0.f, 0.f, 0.f};
    f32x4 acc[4][4];
    for (int i = 0; i < 4; i++)
        for (int j = 0; j < 4; j++) acc[i][j] = zero4;

    for (int k0 = 0; k0 < K; k0 += 32) {
        __syncthreads();
        for (int i = 0; i < 2; i++) {
            int id = i * 256 + tid;
            int row = id >> 2, c = id & 3;
            uint4 va = *(const uint4*)(A + (size_t)(m0 + row) * K + k0 + c * 8);
            *(uint4*)(&As[row * 32 + ((c ^ (row & 3)) << 3)]) = va;
            uint4 vb = *(const uint4*)(B + (size_t)(n0 + row) * K + k0 + c * 8);
            *(uint4*)(&Bs[row * 32 + ((c ^ (row & 3)) << 3)]) = vb;
        }
        __syncthreads();
        bf16x8 af[4], bfr[4];
        int sw = quad ^ (m16 & 3);   // row&3 == m16&3 for all frag rows
        for (int i = 0; i < 4; i++) {
            int ra = wm + i * 16 + m16;
            af[i] = *(const bf16x8*)(&As[ra * 32 + (sw << 3)]);
            int rb = wn + i * 16 + m16;
            bfr[i] = *(const bf16x8*)(&Bs[rb * 32 + (sw << 3)]);
        }
        for (int i = 0; i < 4; i++)
            for (int j = 0; j < 4; j++)
                acc[i][j] = __builtin_amdgcn_mfma_f32_16x16x32_bf16(af[i], bfr[j], acc[i][j], 0, 0, 0);
    }
    for (int i = 0; i < 4; i++)
        for (int j = 0; j < 4; j++)
            for (int r = 0; r < 4; r++) {
                int row = m0 + wm + i * 16 + quad * 4 + r;
                int col = n0 + wn + j * 16 + m16;
                float v = acc[i][j][r];
                if (bf16_out) ((u16*)Cp)[(size_t)row * N + col] = f2b(v);
                else          ((float*)Cp)[(size_t)row * N + col] = v;
            }
}

// ---------------- RoPE (Q and K), bf16 in/out ----------------
__global__ __launch_bounds__(256) void rope_k(const u16* __restrict__ QKV, const int* __restrict__ pos,
                                              u16* __restrict__ Qb, u16* __restrict__ Kb) {
    int id = blockIdx.x * 256 + threadIdx.x;
    const int NQ = S_LEN * NH * 128;   // 4194304
    const u16* src; u16* dst;
    int s, j;
    if (id < NQ) {
        s = id >> 10; int rem = id & 1023; int h = rem >> 7; j = rem & 127;
        src = QKV + (size_t)s * QKVW + h * 256;
        dst = Qb + (size_t)s * QD + h * 256;
    } else {
        int id2 = id - NQ;
        s = id2 >> 9; int rem = id2 & 511; int kvh = rem >> 7; j = rem & 127;
        src = QKV + (size_t)s * QKVW + QD + kvh * 256;
        dst = Kb + (size_t)s * KD + kvh * 256;
    }
    float p = (float)pos[s];
    // inv_freq = 10000^(-j/128) = exp(-j * ln(10000)/128); accurate expf (not __expf):
    float invf = expf(-0.07195578429985445f * (float)j);
    float ang = p * invf;
    float sn, cs;
    sincosf(ang, &sn, &cs);
    float x1 = b2f(src[j]), x2 = b2f(src[j + 128]);
    dst[j]       = f2b(x1 * cs - x2 * sn);
    dst[j + 128] = f2b(x2 * cs + x1 * sn);
}

// ---------------- V transpose: QKV[:, 3072+d] -> Vt[d][s] (bf16) ----------------
__global__ __launch_bounds__(256) void vtrans(const u16* __restrict__ QKV, u16* __restrict__ Vt) {
    const int s0 = blockIdx.x * 64, d0 = blockIdx.y * 64;
    __shared__ u16 T[64][72];
    const int t = threadIdx.x;
    for (int i = 0; i < 2; i++) {
        int id = i * 256 + t;
        int r = id >> 3, c = id & 7;
        uint4 v = *(const uint4*)(QKV + (size_t)(s0 + r) * QKVW + (QD + KD) + d0 + c * 8);
        *(uint4*)(&T[r][c * 8]) = v;
    }
    __syncthreads();
    for (int i = 0; i < 2; i++) {
        int id = i * 256 + t;
        int r = id >> 3, c = id & 7;    // r = local d row, c = s chunk
        union { u16 u[8]; uint4 v; } o;
        for (int jj = 0; jj < 8; jj++) o.u[jj] = T[c * 8 + jj][r];
        *(uint4*)(Vt + (size_t)(d0 + r) * S_LEN + s0 + c * 8) = o.v;
    }
}

// ---------------- flash attention with softcap + causal mask ----------------
// block = (qtile of 64 rows, head). 4 waves x 16 q-rows. kv tiles of 64.
// LDS: Klds 64x256 (32KB) + Vlds[d][kv] 256x64 (32KB) = 64KB; P aliases Klds (wave-private 2KB).
__global__ __launch_bounds__(256) void attn(const u16* __restrict__ Qb, const u16* __restrict__ Kb,
                                            const u16* __restrict__ Vt, u16* __restrict__ Ctx) {
    const int tid  = threadIdx.x;
    const int wave = tid >> 6, lane = tid & 63;
    const int quad = lane >> 4, m16 = lane & 15;
    const int qt = blockIdx.x, h = blockIdx.y, kvh = h >> 1;
    const int q0 = qt * 64;
    __shared__ u16 Klds[64 * 256];
    __shared__ u16 Vlds[256 * 64];
    u16* Pl = &Klds[wave * 1024];   // wave-private 16x64 P slice (K tile dead by then)
    const f32x4 zero4 = {0.f, 0.f, 0.f, 0.f};

    // Q fragments: 16 rows x 256 d, A-layout (m=lane&15, k=quad*8+j, 8 k-steps)
    bf16x8 qf[8];
    {
        const u16* qp = Qb + (size_t)(q0 + wave * 16 + m16) * QD + h * 256 + quad * 8;
        for (int ks = 0; ks < 8; ks++) qf[ks] = *(const bf16x8*)(qp + ks * 32);
    }
    float mi[4] = {-1e30f, -1e30f, -1e30f, -1e30f};
    float li[4] = {0.f, 0.f, 0.f, 0.f};
    f32x4 o[16];
    for (int i = 0; i < 16; i++) o[i] = zero4;

    for (int kt = 0; kt <= qt; kt++) {
        __syncthreads();   // previous iter's Klds(P)/Vlds reads complete
        {   // stage K tile (64 kv x 256 d) and V tile (256 d x 64 kv), swizzled
            const u16* Ks = Kb + (size_t)(kt * 64) * KD + kvh * 256;
            for (int i = 0; i < 8; i++) {
                int id = i * 256 + tid;
                int kv = id >> 5, c = id & 31;
                uint4 v = *(const uint4*)(Ks + (size_t)kv * KD + c * 8);
                *(uint4*)(&Klds[kv * 256 + ((c ^ (kv & 7)) << 3)]) = v;
            }
            const u16* Vs = Vt + (size_t)(kvh * 256) * S_LEN + kt * 64;
            for (int i = 0; i < 8; i++) {
                int id = i * 256 + tid;
                int d = id >> 3, c = id & 7;
                uint4 v = *(const uint4*)(Vs + (size_t)d * S_LEN + c * 8);
                *(uint4*)(&Vlds[d * 64 + ((c ^ (d & 7)) << 3)]) = v;
            }
        }
        __syncthreads();
        // S = Q K^T  (16 q-rows x 64 kv per wave)
        f32x4 s[4];
        for (int nt = 0; nt < 4; nt++) {
            f32x4 a = zero4;
            int kr = nt * 16 + m16;
            int sw = kr & 7;
            for (int ks = 0; ks < 8; ks++) {
                int c = ks * 4 + quad;
                bf16x8 kf = *(const bf16x8*)(&Klds[kr * 256 + ((c ^ sw) << 3)]);
                a = __builtin_amdgcn_mfma_f32_16x16x32_bf16(qf[ks], kf, a, 0, 0, 0);
            }
            s[nt] = a;
        }
        // softcap (50*tanh(dot*scale/50), scale=1/16 -> x*0.00125) + causal mask on diagonal
        for (int nt = 0; nt < 4; nt++)
            for (int r = 0; r < 4; r++) {
                float x = s[nt][r] * 0.00125f;
                x = fminf(fmaxf(x, -10.f), 10.f);
                float e = __expf(2.f * x);
                float v = 50.f * (e - 1.f) / (e + 1.f);
                if (kt == qt) {
                    int mg = wave * 16 + quad * 4 + r;
                    int ng = nt * 16 + m16;
                    if (ng > mg) v = -1e30f;
                }
                s[nt][r] = v;
            }
        // online softmax (row stats across the 16 lanes of each quad)
        float alpha[4];
        for (int r = 0; r < 4; r++) {
            float mx = fmaxf(fmaxf(s[0][r], s[1][r]), fmaxf(s[2][r], s[3][r]));
            mx = fmaxf(mx, __shfl_xor(mx, 1));
            mx = fmaxf(mx, __shfl_xor(mx, 2));
            mx = fmaxf(mx, __shfl_xor(mx, 4));
            mx = fmaxf(mx, __shfl_xor(mx, 8));
            float mn = fmaxf(mi[r], mx);
            alpha[r] = __expf(mi[r] - mn);
            float rs = 0.f;
            for (int nt = 0; nt < 4; nt++) {
                float p = __expf(s[nt][r] - mn);
                s[nt][r] = p;
                rs += p;
            }
            rs += __shfl_xor(rs, 1);
            rs += __shfl_xor(rs, 2);
            rs += __shfl_xor(rs, 4);
            rs += __shfl_xor(rs, 8);
            li[r] = li[r] * alpha[r] + rs;
            mi[r] = mn;
        }
        for (int dt = 0; dt < 16; dt++)
            for (int r = 0; r < 4; r++) o[dt][r] *= alpha[r];
        __syncthreads();   // all waves' Klds reads done before P overwrites it
        // P: C-layout regs -> LDS (bf16) -> A-layout frags (m120-verified round trip)
        for (int nt = 0; nt < 4; nt++)
            for (int r = 0; r < 4; r++) {
                int m = quad * 4 + r;
                int col = nt * 16 + m16;
                int c = col >> 3, off = col & 7;
                Pl[m * 64 + ((c ^ (m & 7)) << 3) + off] = f2b(s[nt][r]);
            }
        bf16x8 pf[2];
        for (int t = 0; t < 2; t++) {
            int c = t * 4 + quad;
            pf[t] = *(const bf16x8*)(&Pl[m16 * 64 + ((c ^ (m16 & 7)) << 3)]);
        }
        // O += P V
        for (int dt = 0; dt < 16; dt++) {
            int d = dt * 16 + m16;
            int sw = d & 7;
            for (int t = 0; t < 2; t++) {
                int c = t * 4 + quad;
                bf16x8 vf = *(const bf16x8*)(&Vlds[d * 64 + ((c ^ sw) << 3)]);
                o[dt] = __builtin_amdgcn_mfma_f32_16x16x32_bf16(pf[t], vf, o[dt], 0, 0, 0);
            }
        }
    }
    float inv[4];
    for (int r = 0; r < 4; r++) inv[r] = 1.f / li[r];
    for (int dt = 0; dt < 16; dt++)
        for (int r = 0; r < 4; r++) {
            int row = q0 + wave * 16 + quad * 4 + r;
            int col = dt * 16 + m16;
            Ctx[(size_t)row * QD + h * 256 + col] = f2b(o[dt][r] * inv[r]);
        }
}

// ---------------- launch ----------------
extern "C" void kernel_launch(void* const* d_in, const int* in_sizes, int n_in,
                              void* d_out, int out_size, void* d_ws, size_t ws_size,
                              hipStream_t stream) {
    const float* H  = (const float*)d_in[0];
    const float* Wq = (const float*)d_in[1];
    const float* Wk = (const float*)d_in[2];
    const float* Wv = (const float*)d_in[3];
    const float* Wo = (const float*)d_in[4];
    const int* pos  = (const int*)d_in[5];
    float* out = (float*)d_out;

    char* ws = (char*)d_ws;
    size_t off = 0;
    u16* Hb     = (u16*)(ws + off); off += (size_t)S_LEN * HID * 2;        // 18.9MB
    u16* Wqkvt  = (u16*)(ws + off); off += (size_t)QKVW * HID * 2;         // 18.9MB
    u16* Wot    = (u16*)(ws + off); off += (size_t)HID * QD * 2;           // 9.4MB
    u16* QKVraw = (u16*)(ws + off); off += (size_t)S_LEN * QKVW * 2;       // 33.6MB
    u16* Qb     = (u16*)(ws + off); off += (size_t)S_LEN * QD * 2;         // 16.8MB
    u16* Kb     = (u16*)(ws + off); off += (size_t)S_LEN * KD * 2;         // 8.4MB
    u16* Vt     = (u16*)(ws + off); off += (size_t)KD * S_LEN * 2;         // 8.4MB
    u16* Ctx    = (u16*)(ws + off); off += (size_t)S_LEN * QD * 2;         // 16.8MB

    // 1. hidden -> bf16
    cvt_h<<<dim3((S_LEN * HID / 4 + 255) / 256), dim3(256), 0, stream>>>(H, Hb, S_LEN * HID / 4);
    // 2. weights -> transposed bf16 (Wq/Wk/Wv fused into one [4096][2304])
    twcvt<<<dim3(QD / 64, HID / 64), dim3(256), 0, stream>>>(Wq, Wqkvt, HID, QD, HID);
    twcvt<<<dim3(KD / 64, HID / 64), dim3(256), 0, stream>>>(Wk, Wqkvt + (size_t)QD * HID, HID, KD, HID);
    twcvt<<<dim3(KD / 64, HID / 64), dim3(256), 0, stream>>>(Wv, Wqkvt + (size_t)(QD + KD) * HID, HID, KD, HID);
    twcvt<<<dim3(HID / 64, QD / 64), dim3(256), 0, stream>>>(Wo, Wot, QD, HID, QD);
    // 3. fused QKV projection: [4096][4096] bf16
    gemm_bt<<<dim3(QKVW / 128, S_LEN / 128), dim3(256), 0, stream>>>(Hb, Wqkvt, QKVraw, S_LEN, QKVW, HID, 1);
    // 4. RoPE on Q and K
    rope_k<<<dim3((S_LEN * NH * 128 + S_LEN * NKV * 128) / 256), dim3(256), 0, stream>>>(QKVraw, pos, Qb, Kb);
    // 5. V -> [d][s]
    vtrans<<<dim3(S_LEN / 64, KD / 64), dim3(256), 0, stream>>>(QKVraw, Vt);
    // 6. flash attention
    attn<<<dim3(S_LEN / 64, NH), dim3(256), 0, stream>>>(Qb, Kb, Vt, Ctx);
    // 7. output projection -> f32 d_out
    gemm_bt<<<dim3(HID / 128, S_LEN / 128), dim3(256), 0, stream>>>(Ctx, Wot, out, S_LEN, HID, QD, 0);
}

// Round 3
// 1552.742 us; speedup vs baseline: 1.4665x; 1.4665x over previous
//
#include <hip/hip_runtime.h>
#include <cstdint>
#include <cstddef>

typedef unsigned short u16;
typedef short bf16x8 __attribute__((ext_vector_type(8)));
typedef float f32x4 __attribute__((ext_vector_type(4)));

#define S_LEN 4096
#define HID   2304
#define NH    8
#define NKV   4
#define HD    256
#define QD    2048   // NH*HD
#define KD    1024   // NKV*HD
#define QKVW  4096   // QD + KD + KD

__device__ __forceinline__ u16 f2b(float f) {
    union { float f; uint32_t u; } v; v.f = f;
    uint32_t r = (v.u + 0x7FFFu + ((v.u >> 16) & 1u)) >> 16;
    return (u16)r;
}
__device__ __forceinline__ float b2f(u16 u) {
    union { uint32_t u; float f; } v; v.u = ((uint32_t)u) << 16;
    return v.f;
}

// async global->LDS, 16B per lane; LDS dest = wave-uniform base + lane*16
__device__ __forceinline__ void glds16(const void* g, void* l) {
    __builtin_amdgcn_global_load_lds(
        (__attribute__((address_space(1))) void*)(const_cast<void*>(g)),
        (__attribute__((address_space(3))) void*)l, 16, 0, 0);
}

// ---------------- fp32 -> bf16 convert (hidden states) ----------------
__global__ __launch_bounds__(256) void cvt_h(const float* __restrict__ in, u16* __restrict__ out, int n4) {
    int id = blockIdx.x * 256 + threadIdx.x;
    if (id >= n4) return;
    float4 v = ((const float4*)in)[id];
    uint2 o;
    o.x = (uint32_t)f2b(v.x) | ((uint32_t)f2b(v.y) << 16);
    o.y = (uint32_t)f2b(v.z) | ((uint32_t)f2b(v.w) << 16);
    ((uint2*)out)[id] = o;
}

// ---------------- weight transpose+convert: W[K][N] f32 -> out[n][k] bf16 ----------------
__global__ __launch_bounds__(256) void twcvt(const float* __restrict__ W, u16* __restrict__ out,
                                             int K, int N, int ldo) {
    const int n0 = blockIdx.x * 64, k0 = blockIdx.y * 64;
    __shared__ float T[64][68];
    const int t = threadIdx.x;
    for (int i = 0; i < 4; i++) {
        int id = i * 256 + t;
        int r = id >> 4, c4 = id & 15;
        float4 v = *(const float4*)(W + (size_t)(k0 + r) * N + n0 + c4 * 4);
        *(float4*)(&T[r][c4 * 4]) = v;
    }
    __syncthreads();
    for (int i = 0; i < 4; i++) {
        int id = i * 256 + t;
        int rn = id >> 4, c4 = id & 15;
        u16 a = f2b(T[c4 * 4 + 0][rn]);
        u16 b = f2b(T[c4 * 4 + 1][rn]);
        u16 c = f2b(T[c4 * 4 + 2][rn]);
        u16 d = f2b(T[c4 * 4 + 3][rn]);
        uint2 o;
        o.x = (uint32_t)a | ((uint32_t)b << 16);
        o.y = (uint32_t)c | ((uint32_t)d << 16);
        *(uint2*)(out + (size_t)(n0 + rn) * ldo + k0 + c4 * 4) = o;
    }
}

// ---------------- GEMM: C[M][N] = A[M][K] * B[N][K]^T, bf16 in, f32 acc ----------------
// m97 structure: 128x128 tile, BK=32, global_load_lds width-16 staging, XOR-swizzled LDS.
__global__ __launch_bounds__(256) void gemm_bt(const u16* __restrict__ A, const u16* __restrict__ B,
                                               void* __restrict__ Cp, int M, int N, int K, int bf16_out) {
    const int tid  = threadIdx.x;
    const int wv = tid >> 6, lane = tid & 63;
    const int quad = lane >> 4, m16 = lane & 15;
    const int m0 = blockIdx.y * 128, n0 = blockIdx.x * 128;
    const int wm = (wv & 1) * 64, wn = (wv >> 1) * 64;
    __shared__ __align__(16) u16 As[128 * 32];
    __shared__ __align__(16) u16 Bs[128 * 32];
    // staging map: LDS slot s holds global chunk (row=s>>2, c=(s&3)^(row&3)) -> swizzled layout
    const u16* pA[2]; const u16* pB[2];
    for (int i = 0; i < 2; i++) {
        int s = (wv * 2 + i) * 64 + lane;
        int row = s >> 2, c = (s & 3) ^ (row & 3);
        pA[i] = A + (size_t)(m0 + row) * K + c * 8;
        pB[i] = B + (size_t)(n0 + row) * K + c * 8;
    }
    const f32x4 zero4 = {0.f, 0.f, 0.f, 0.f};
    f32x4 acc[4][4];
    for (int i = 0; i < 4; i++)
        for (int j = 0; j < 4; j++) acc[i][j] = zero4;

    for (int k0 = 0; k0 < K; k0 += 32) {
        __syncthreads();
        for (int i = 0; i < 2; i++) {
            glds16(pA[i] + k0, &As[(wv * 2 + i) * 512]);
            glds16(pB[i] + k0, &Bs[(wv * 2 + i) * 512]);
        }
        __syncthreads();   // drains vmcnt(0): staged data visible
        bf16x8 af[4], bfr[4];
        int sw = quad ^ (m16 & 3);   // row&3 == m16&3 for all frag rows
        for (int i = 0; i < 4; i++) {
            int ra = wm + i * 16 + m16;
            af[i] = *(const bf16x8*)(&As[ra * 32 + (sw << 3)]);
            int rb = wn + i * 16 + m16;
            bfr[i] = *(const bf16x8*)(&Bs[rb * 32 + (sw << 3)]);
        }
        for (int i = 0; i < 4; i++)
            for (int j = 0; j < 4; j++)
                acc[i][j] = __builtin_amdgcn_mfma_f32_16x16x32_bf16(af[i], bfr[j], acc[i][j], 0, 0, 0);
    }
    for (int i = 0; i < 4; i++)
        for (int j = 0; j < 4; j++)
            for (int r = 0; r < 4; r++) {
                int row = m0 + wm + i * 16 + quad * 4 + r;
                int col = n0 + wn + j * 16 + m16;
                float v = acc[i][j][r];
                if (bf16_out) ((u16*)Cp)[(size_t)row * N + col] = f2b(v);
                else          ((float*)Cp)[(size_t)row * N + col] = v;
            }
}

// ---------------- RoPE (Q and K), bf16 in/out ----------------
__global__ __launch_bounds__(256) void rope_k(const u16* __restrict__ QKV, const int* __restrict__ pos,
                                              u16* __restrict__ Qb, u16* __restrict__ Kb) {
    int id = blockIdx.x * 256 + threadIdx.x;
    const int NQ = S_LEN * NH * 128;
    const u16* src; u16* dst;
    int s, j;
    if (id < NQ) {
        s = id >> 10; int rem = id & 1023; int h = rem >> 7; j = rem & 127;
        src = QKV + (size_t)s * QKVW + h * 256;
        dst = Qb + (size_t)s * QD + h * 256;
    } else {
        int id2 = id - NQ;
        s = id2 >> 9; int rem = id2 & 511; int kvh = rem >> 7; j = rem & 127;
        src = QKV + (size_t)s * QKVW + QD + kvh * 256;
        dst = Kb + (size_t)s * KD + kvh * 256;
    }
    float p = (float)pos[s];
    float invf = expf(-0.07195578429985445f * (float)j);
    float ang = p * invf;
    float sn, cs;
    sincosf(ang, &sn, &cs);
    float x1 = b2f(src[j]), x2 = b2f(src[j + 128]);
    dst[j]       = f2b(x1 * cs - x2 * sn);
    dst[j + 128] = f2b(x2 * cs + x1 * sn);
}

// ---------------- V transpose: QKV[:, 3072+d] -> Vt[d][s] (bf16) ----------------
__global__ __launch_bounds__(256) void vtrans(const u16* __restrict__ QKV, u16* __restrict__ Vt) {
    const int s0 = blockIdx.x * 64, d0 = blockIdx.y * 64;
    __shared__ u16 T[64][72];
    const int t = threadIdx.x;
    for (int i = 0; i < 2; i++) {
        int id = i * 256 + t;
        int r = id >> 3, c = id & 7;
        uint4 v = *(const uint4*)(QKV + (size_t)(s0 + r) * QKVW + (QD + KD) + d0 + c * 8);
        *(uint4*)(&T[r][c * 8]) = v;
    }
    __syncthreads();
    for (int i = 0; i < 2; i++) {
        int id = i * 256 + t;
        int r = id >> 3, c = id & 7;
        union { u16 u[8]; uint4 v; } o;
        for (int jj = 0; jj < 8; jj++) o.u[jj] = T[c * 8 + jj][r];
        *(uint4*)(Vt + (size_t)(d0 + r) * S_LEN + s0 + c * 8) = o.v;
    }
}

// ---------------- flash attention, softcap + causal, fixed-max softmax ----------------
// Softcap bounds scores to [-50,50] -> p = exp(s) never overflows (e^50=5e21, sum<=2e25 in f32),
// so NO running max, NO rescale, NO per-tile reductions; l reduced once at the end.
// kv-tile=32, double-buffered K/V staged via global_load_lds, dedicated P buffer -> 1 barrier/tile.
__global__ __launch_bounds__(256) void attn(const u16* __restrict__ Qb, const u16* __restrict__ Kb,
                                            const u16* __restrict__ Vt, u16* __restrict__ Ctx) {
    const int tid  = threadIdx.x;
    const int wv = tid >> 6, lane = tid & 63;
    const int quad = lane >> 4, m16 = lane & 15;
    // load-balanced decode: pair (h, qt) with (h+4, 63-qt) -> co-resident pairs sum to const work
    int bx = blockIdx.x;
    int half = bx >> 8, i0 = bx & 255;
    const int h  = (i0 >> 6) + half * 4;
    const int qt = half ? (63 - (i0 & 63)) : (i0 & 63);
    const int kvh = h >> 1;
    const int q0 = qt * 64;
    const int ntiles = 2 * qt + 2;

    __shared__ __align__(16) u16 Kl[2][32 * 256];   // [buf][kv][d-chunks swizzled]
    __shared__ __align__(16) u16 Vl[2][256 * 32];   // [buf][d][kv-chunks swizzled]
    __shared__ __align__(16) u16 Pl[4][16 * 32];    // wave-private P

    // glds gather maps (choose global chunk per lane so landing order IS the swizzled layout):
    // K: slot s -> (kv=s>>5, c=(s&31)^(kv&7));  V: slot s -> (d=s>>2, cc=(s&3)^(d&3))
    const u16* pK[4]; const u16* pV[4];
    for (int i = 0; i < 4; i++) {
        int s = (wv * 4 + i) * 64 + lane;
        int kv = s >> 5, c = (s & 31) ^ (kv & 7);
        pK[i] = Kb + (size_t)kv * KD + kvh * 256 + c * 8;
        int d = s >> 2, cc = (s & 3) ^ (d & 3);
        pV[i] = Vt + (size_t)(kvh * 256 + d) * S_LEN + cc * 8;   // FIX: kvh*256 row offset
    }
    // Q fragments: 16 rows x 256 d, A-layout
    bf16x8 qf[8];
    {
        const u16* qp = Qb + (size_t)(q0 + wv * 16 + m16) * QD + h * 256 + quad * 8;
        for (int ks = 0; ks < 8; ks++) qf[ks] = *(const bf16x8*)(qp + ks * 32);
    }
    float li[4] = {0.f, 0.f, 0.f, 0.f};
    f32x4 o[16];
    for (int i = 0; i < 16; i++) o[i] = (f32x4){0.f, 0.f, 0.f, 0.f};

    // prologue: stage tile 0 into buf 0
    for (int i = 0; i < 4; i++) {
        glds16(pK[i], &Kl[0][(wv * 4 + i) * 512]);
        glds16(pV[i], &Vl[0][(wv * 4 + i) * 512]);
    }
    __syncthreads();

    for (int kt = 0; kt < ntiles; kt++) {
        const int cur = kt & 1, nxt = cur ^ 1;
        if (kt + 1 < ntiles) {   // async prefetch next tile (overlaps with all compute below)
            size_t koff = (size_t)(kt + 1) * 32 * KD;
            int    voff = (kt + 1) * 32;
            for (int i = 0; i < 4; i++) {
                glds16(pK[i] + koff, &Kl[nxt][(wv * 4 + i) * 512]);
                glds16(pV[i] + voff, &Vl[nxt][(wv * 4 + i) * 512]);
            }
        }
        // S = Q K^T (16 q-rows x 32 kv per wave)
        f32x4 s[2];
        for (int nt = 0; nt < 2; nt++) {
            f32x4 a = (f32x4){0.f, 0.f, 0.f, 0.f};
            int kr = nt * 16 + m16;
            int sw = kr & 7;
            for (int ks = 0; ks < 8; ks++) {
                int c = ks * 4 + quad;
                bf16x8 kf = *(const bf16x8*)(&Kl[cur][kr * 256 + ((c ^ sw) << 3)]);
                a = __builtin_amdgcn_mfma_f32_16x16x32_bf16(qf[ks], kf, a, 0, 0, 0);
            }
            s[nt] = a;
        }
        // softcap -> p = exp(v), mask, accumulate l (no reductions, no rescale)
        const int kvbase = kt * 32;
        for (int nt = 0; nt < 2; nt++)
            for (int r = 0; r < 4; r++) {
                float x2 = s[nt][r] * 0.0025f;              // 2 * (dot*scale)/50
                x2 = fminf(fmaxf(x2, -20.f), 20.f);
                float e = __expf(x2);
                float t = (e - 1.f) * __builtin_amdgcn_rcpf(e + 1.f);
                float p = __expf(50.f * t);
                int kvg = kvbase + nt * 16 + m16;
                int qg  = q0 + wv * 16 + quad * 4 + r;
                p = (kvg > qg) ? 0.f : p;
                li[r] += p;
                s[nt][r] = p;
            }
        // P: C-layout -> LDS (wave-private, no barrier) -> A-layout frag
        u16* Pw = &Pl[wv][0];
        for (int nt = 0; nt < 2; nt++)
            for (int r = 0; r < 4; r++) {
                int m = quad * 4 + r;
                int col = nt * 16 + m16;
                int c = col >> 3, off = col & 7;
                Pw[m * 32 + ((c ^ (m & 3)) << 3) + off] = f2b(s[nt][r]);
            }
        bf16x8 pf = *(const bf16x8*)(&Pw[m16 * 32 + ((quad ^ (m16 & 3)) << 3)]);
        // O += P V
        for (int dt = 0; dt < 16; dt++) {
            int d = dt * 16 + m16;
            bf16x8 vf = *(const bf16x8*)(&Vl[cur][d * 32 + ((quad ^ (d & 3)) << 3)]);
            o[dt] = __builtin_amdgcn_mfma_f32_16x16x32_bf16(pf, vf, o[dt], 0, 0, 0);
        }
        __syncthreads();   // single barrier: cur-buf reads done + nxt-buf glds drained (vmcnt(0))
    }
    // final l reduction across the 16 lanes holding each row, then normalize + store
    float inv[4];
    for (int r = 0; r < 4; r++) {
        float l = li[r];
        l += __shfl_xor(l, 1); l += __shfl_xor(l, 2);
        l += __shfl_xor(l, 4); l += __shfl_xor(l, 8);
        inv[r] = 1.f / l;
    }
    for (int dt = 0; dt < 16; dt++)
        for (int r = 0; r < 4; r++) {
            int row = q0 + wv * 16 + quad * 4 + r;
            int col = dt * 16 + m16;
            Ctx[(size_t)row * QD + h * 256 + col] = f2b(o[dt][r] * inv[r]);
        }
}

// ---------------- launch ----------------
extern "C" void kernel_launch(void* const* d_in, const int* in_sizes, int n_in,
                              void* d_out, int out_size, void* d_ws, size_t ws_size,
                              hipStream_t stream) {
    const float* H  = (const float*)d_in[0];
    const float* Wq = (const float*)d_in[1];
    const float* Wk = (const float*)d_in[2];
    const float* Wv = (const float*)d_in[3];
    const float* Wo = (const float*)d_in[4];
    const int* pos  = (const int*)d_in[5];
    float* out = (float*)d_out;

    char* ws = (char*)d_ws;
    size_t off = 0;
    u16* Hb     = (u16*)(ws + off); off += (size_t)S_LEN * HID * 2;
    u16* Wqkvt  = (u16*)(ws + off); off += (size_t)QKVW * HID * 2;
    u16* Wot    = (u16*)(ws + off); off += (size_t)HID * QD * 2;
    u16* QKVraw = (u16*)(ws + off); off += (size_t)S_LEN * QKVW * 2;
    u16* Qb     = (u16*)(ws + off); off += (size_t)S_LEN * QD * 2;
    u16* Kb     = (u16*)(ws + off); off += (size_t)S_LEN * KD * 2;
    u16* Vt     = (u16*)(ws + off); off += (size_t)KD * S_LEN * 2;
    u16* Ctx    = (u16*)(ws + off); off += (size_t)S_LEN * QD * 2;

    cvt_h<<<dim3((S_LEN * HID / 4 + 255) / 256), dim3(256), 0, stream>>>(H, Hb, S_LEN * HID / 4);
    twcvt<<<dim3(QD / 64, HID / 64), dim3(256), 0, stream>>>(Wq, Wqkvt, HID, QD, HID);
    twcvt<<<dim3(KD / 64, HID / 64), dim3(256), 0, stream>>>(Wk, Wqkvt + (size_t)QD * HID, HID, KD, HID);
    twcvt<<<dim3(KD / 64, HID / 64), dim3(256), 0, stream>>>(Wv, Wqkvt + (size_t)(QD + KD) * HID, HID, KD, HID);
    twcvt<<<dim3(HID / 64, QD / 64), dim3(256), 0, stream>>>(Wo, Wot, QD, HID, QD);
    gemm_bt<<<dim3(QKVW / 128, S_LEN / 128), dim3(256), 0, stream>>>(Hb, Wqkvt, QKVraw, S_LEN, QKVW, HID, 1);
    rope_k<<<dim3((S_LEN * NH * 128 + S_LEN * NKV * 128) / 256), dim3(256), 0, stream>>>(QKVraw, pos, Qb, Kb);
    vtrans<<<dim3(S_LEN / 64, KD / 64), dim3(256), 0, stream>>>(QKVraw, Vt);
    attn<<<dim3(512), dim3(256), 0, stream>>>(Qb, Kb, Vt, Ctx);
    gemm_bt<<<dim3(HID / 128, S_LEN / 128), dim3(256), 0, stream>>>(Ctx, Wot, out, S_LEN, HID, QD, 0);
}

// Round 4
// 573.136 us; speedup vs baseline: 3.9730x; 2.7092x over previous
//
#include <hip/hip_runtime.h>
#include <cstdint>
#include <cstddef>

typedef unsigned short u16;
typedef short bf16x8 __attribute__((ext_vector_type(8)));
typedef float f32x4 __attribute__((ext_vector_type(4)));

#define S_LEN 4096
#define HID   2304
#define NH    8
#define NKV   4
#define HD    256
#define QD    2048   // NH*HD
#define KD    1024   // NKV*HD
#define QKVW  4096   // QD + KD + KD

__device__ __forceinline__ u16 f2b(float f) {
    union { float f; uint32_t u; } v; v.f = f;
    uint32_t r = (v.u + 0x7FFFu + ((v.u >> 16) & 1u)) >> 16;
    return (u16)r;
}
__device__ __forceinline__ float b2f(u16 u) {
    union { uint32_t u; float f; } v; v.u = ((uint32_t)u) << 16;
    return v.f;
}

// async global->LDS, 16B per lane; LDS dest = wave-uniform base + lane*16
__device__ __forceinline__ void glds16(const void* g, void* l) {
    __builtin_amdgcn_global_load_lds(
        (__attribute__((address_space(1))) void*)(const_cast<void*>(g)),
        (__attribute__((address_space(3))) void*)l, 16, 0, 0);
}

// ---------------- fp32 -> bf16 convert (hidden states) ----------------
__global__ __launch_bounds__(256) void cvt_h(const float* __restrict__ in, u16* __restrict__ out, int n4) {
    int id = blockIdx.x * 256 + threadIdx.x;
    if (id >= n4) return;
    float4 v = ((const float4*)in)[id];
    uint2 o;
    o.x = (uint32_t)f2b(v.x) | ((uint32_t)f2b(v.y) << 16);
    o.y = (uint32_t)f2b(v.z) | ((uint32_t)f2b(v.w) << 16);
    ((uint2*)out)[id] = o;
}

// ---------------- weight transpose+convert: W[K][N] f32 -> out[n][k] bf16 ----------------
__global__ __launch_bounds__(256) void twcvt(const float* __restrict__ W, u16* __restrict__ out,
                                             int K, int N, int ldo) {
    const int n0 = blockIdx.x * 64, k0 = blockIdx.y * 64;
    __shared__ float T[64][68];
    const int t = threadIdx.x;
    for (int i = 0; i < 4; i++) {
        int id = i * 256 + t;
        int r = id >> 4, c4 = id & 15;
        float4 v = *(const float4*)(W + (size_t)(k0 + r) * N + n0 + c4 * 4);
        *(float4*)(&T[r][c4 * 4]) = v;
    }
    __syncthreads();
    for (int i = 0; i < 4; i++) {
        int id = i * 256 + t;
        int rn = id >> 4, c4 = id & 15;
        u16 a = f2b(T[c4 * 4 + 0][rn]);
        u16 b = f2b(T[c4 * 4 + 1][rn]);
        u16 c = f2b(T[c4 * 4 + 2][rn]);
        u16 d = f2b(T[c4 * 4 + 3][rn]);
        uint2 o;
        o.x = (uint32_t)a | ((uint32_t)b << 16);
        o.y = (uint32_t)c | ((uint32_t)d << 16);
        *(uint2*)(out + (size_t)(n0 + rn) * ldo + k0 + c4 * 4) = o;
    }
}

// ---------------- GEMM: C[M][N] = A[M][K] * B[N][K]^T, bf16 in, f32 acc ----------------
// m97 structure: 128x128 tile, BK=32, global_load_lds width-16 staging, XOR-swizzled LDS.
// R4: fully manual-unrolled MFMA block with 16 NAMED accumulators (R3's acc[4][4] array
// ended up in scratch: VGPR_Count=60, 4.3 GB/dispatch scratch write traffic, 700 us).
// __launch_bounds__(256,1) grants RA the full register budget.
template<int BF16_OUT>
__global__ __launch_bounds__(256, 1) void gemm_bt(const u16* __restrict__ A, const u16* __restrict__ B,
                                                  void* __restrict__ Cp, int M, int N, int K) {
    const int tid  = threadIdx.x;
    const int wv = tid >> 6, lane = tid & 63;
    const int quad = lane >> 4, m16 = lane & 15;
    const int m0 = blockIdx.y * 128, n0 = blockIdx.x * 128;
    const int wm = (wv & 1) * 64, wn = (wv >> 1) * 64;
    __shared__ __align__(16) u16 As[128 * 32];
    __shared__ __align__(16) u16 Bs[128 * 32];
    // staging map: LDS slot s holds global chunk (row=s>>2, c=(s&3)^(row&3)) -> swizzled layout
    int s0i = (wv * 2) * 64 + lane, s1i = s0i + 64;
    int row0 = s0i >> 2, c0 = (s0i & 3) ^ (row0 & 3);
    int row1 = s1i >> 2, c1 = (s1i & 3) ^ (row1 & 3);
    const u16* pA0 = A + (size_t)(m0 + row0) * K + c0 * 8;
    const u16* pA1 = A + (size_t)(m0 + row1) * K + c1 * 8;
    const u16* pB0 = B + (size_t)(n0 + row0) * K + c0 * 8;
    const u16* pB1 = B + (size_t)(n0 + row1) * K + c1 * 8;
    u16* lA0 = &As[(wv * 2 + 0) * 512]; u16* lA1 = &As[(wv * 2 + 1) * 512];
    u16* lB0 = &Bs[(wv * 2 + 0) * 512]; u16* lB1 = &Bs[(wv * 2 + 1) * 512];

    const f32x4 z4 = {0.f, 0.f, 0.f, 0.f};
    f32x4 acc00 = z4, acc01 = z4, acc02 = z4, acc03 = z4;
    f32x4 acc10 = z4, acc11 = z4, acc12 = z4, acc13 = z4;
    f32x4 acc20 = z4, acc21 = z4, acc22 = z4, acc23 = z4;
    f32x4 acc30 = z4, acc31 = z4, acc32 = z4, acc33 = z4;

    const int sw = quad ^ (m16 & 3);
    const u16* ra0 = &As[(wm + 0 * 16 + m16) * 32 + (sw << 3)];
    const u16* ra1 = &As[(wm + 1 * 16 + m16) * 32 + (sw << 3)];
    const u16* ra2 = &As[(wm + 2 * 16 + m16) * 32 + (sw << 3)];
    const u16* ra3 = &As[(wm + 3 * 16 + m16) * 32 + (sw << 3)];
    const u16* rb0 = &Bs[(wn + 0 * 16 + m16) * 32 + (sw << 3)];
    const u16* rb1 = &Bs[(wn + 1 * 16 + m16) * 32 + (sw << 3)];
    const u16* rb2 = &Bs[(wn + 2 * 16 + m16) * 32 + (sw << 3)];
    const u16* rb3 = &Bs[(wn + 3 * 16 + m16) * 32 + (sw << 3)];

    for (int k0 = 0; k0 < K; k0 += 32) {
        __syncthreads();
        glds16(pA0 + k0, lA0);
        glds16(pA1 + k0, lA1);
        glds16(pB0 + k0, lB0);
        glds16(pB1 + k0, lB1);
        __syncthreads();   // drains vmcnt(0): staged data visible
        bf16x8 af0 = *(const bf16x8*)ra0, af1 = *(const bf16x8*)ra1;
        bf16x8 af2 = *(const bf16x8*)ra2, af3 = *(const bf16x8*)ra3;
        bf16x8 bf0 = *(const bf16x8*)rb0, bf1 = *(const bf16x8*)rb1;
        bf16x8 bf2 = *(const bf16x8*)rb2, bf3 = *(const bf16x8*)rb3;
        acc00 = __builtin_amdgcn_mfma_f32_16x16x32_bf16(af0, bf0, acc00, 0, 0, 0);
        acc01 = __builtin_amdgcn_mfma_f32_16x16x32_bf16(af0, bf1, acc01, 0, 0, 0);
        acc02 = __builtin_amdgcn_mfma_f32_16x16x32_bf16(af0, bf2, acc02, 0, 0, 0);
        acc03 = __builtin_amdgcn_mfma_f32_16x16x32_bf16(af0, bf3, acc03, 0, 0, 0);
        acc10 = __builtin_amdgcn_mfma_f32_16x16x32_bf16(af1, bf0, acc10, 0, 0, 0);
        acc11 = __builtin_amdgcn_mfma_f32_16x16x32_bf16(af1, bf1, acc11, 0, 0, 0);
        acc12 = __builtin_amdgcn_mfma_f32_16x16x32_bf16(af1, bf2, acc12, 0, 0, 0);
        acc13 = __builtin_amdgcn_mfma_f32_16x16x32_bf16(af1, bf3, acc13, 0, 0, 0);
        acc20 = __builtin_amdgcn_mfma_f32_16x16x32_bf16(af2, bf0, acc20, 0, 0, 0);
        acc21 = __builtin_amdgcn_mfma_f32_16x16x32_bf16(af2, bf1, acc21, 0, 0, 0);
        acc22 = __builtin_amdgcn_mfma_f32_16x16x32_bf16(af2, bf2, acc22, 0, 0, 0);
        acc23 = __builtin_amdgcn_mfma_f32_16x16x32_bf16(af2, bf3, acc23, 0, 0, 0);
        acc30 = __builtin_amdgcn_mfma_f32_16x16x32_bf16(af3, bf0, acc30, 0, 0, 0);
        acc31 = __builtin_amdgcn_mfma_f32_16x16x32_bf16(af3, bf1, acc31, 0, 0, 0);
        acc32 = __builtin_amdgcn_mfma_f32_16x16x32_bf16(af3, bf2, acc32, 0, 0, 0);
        acc33 = __builtin_amdgcn_mfma_f32_16x16x32_bf16(af3, bf3, acc33, 0, 0, 0);
    }

#define STORE_TILE(I, J, ACC)                                              \
    {                                                                      \
        _Pragma("unroll")                                                  \
        for (int r = 0; r < 4; r++) {                                      \
            int row = m0 + wm + (I) * 16 + quad * 4 + r;                   \
            int col = n0 + wn + (J) * 16 + m16;                            \
            float v = (ACC)[r];                                            \
            if (BF16_OUT) ((u16*)Cp)[(size_t)row * N + col] = f2b(v);      \
            else          ((float*)Cp)[(size_t)row * N + col] = v;         \
        }                                                                  \
    }
    STORE_TILE(0, 0, acc00) STORE_TILE(0, 1, acc01) STORE_TILE(0, 2, acc02) STORE_TILE(0, 3, acc03)
    STORE_TILE(1, 0, acc10) STORE_TILE(1, 1, acc11) STORE_TILE(1, 2, acc12) STORE_TILE(1, 3, acc13)
    STORE_TILE(2, 0, acc20) STORE_TILE(2, 1, acc21) STORE_TILE(2, 2, acc22) STORE_TILE(2, 3, acc23)
    STORE_TILE(3, 0, acc30) STORE_TILE(3, 1, acc31) STORE_TILE(3, 2, acc32) STORE_TILE(3, 3, acc33)
#undef STORE_TILE
}

// ---------------- RoPE (Q and K), bf16 in/out ----------------
__global__ __launch_bounds__(256) void rope_k(const u16* __restrict__ QKV, const int* __restrict__ pos,
                                              u16* __restrict__ Qb, u16* __restrict__ Kb) {
    int id = blockIdx.x * 256 + threadIdx.x;
    const int NQ = S_LEN * NH * 128;
    const u16* src; u16* dst;
    int s, j;
    if (id < NQ) {
        s = id >> 10; int rem = id & 1023; int h = rem >> 7; j = rem & 127;
        src = QKV + (size_t)s * QKVW + h * 256;
        dst = Qb + (size_t)s * QD + h * 256;
    } else {
        int id2 = id - NQ;
        s = id2 >> 9; int rem = id2 & 511; int kvh = rem >> 7; j = rem & 127;
        src = QKV + (size_t)s * QKVW + QD + kvh * 256;
        dst = Kb + (size_t)s * KD + kvh * 256;
    }
    float p = (float)pos[s];
    float invf = expf(-0.07195578429985445f * (float)j);
    float ang = p * invf;
    float sn, cs;
    sincosf(ang, &sn, &cs);
    float x1 = b2f(src[j]), x2 = b2f(src[j + 128]);
    dst[j]       = f2b(x1 * cs - x2 * sn);
    dst[j + 128] = f2b(x2 * cs + x1 * sn);
}

// ---------------- V transpose: QKV[:, 3072+d] -> Vt[d][s] (bf16) ----------------
__global__ __launch_bounds__(256) void vtrans(const u16* __restrict__ QKV, u16* __restrict__ Vt) {
    const int s0 = blockIdx.x * 64, d0 = blockIdx.y * 64;
    __shared__ u16 T[64][72];
    const int t = threadIdx.x;
    for (int i = 0; i < 2; i++) {
        int id = i * 256 + t;
        int r = id >> 3, c = id & 7;
        uint4 v = *(const uint4*)(QKV + (size_t)(s0 + r) * QKVW + (QD + KD) + d0 + c * 8);
        *(uint4*)(&T[r][c * 8]) = v;
    }
    __syncthreads();
    for (int i = 0; i < 2; i++) {
        int id = i * 256 + t;
        int r = id >> 3, c = id & 7;
        union { u16 u[8]; uint4 v; } o;
        for (int jj = 0; jj < 8; jj++) o.u[jj] = T[c * 8 + jj][r];
        *(uint4*)(Vt + (size_t)(d0 + r) * S_LEN + s0 + c * 8) = o.v;
    }
}

// ---------------- flash attention, softcap + causal, fixed-max softmax ----------------
// Softcap bounds scores to [-50,50] -> p = exp(s) never overflows (e^50=5e21, sum<=2e25 in f32),
// so NO running max, NO rescale, NO per-tile reductions; l reduced once at the end.
// kv-tile=32, double-buffered K/V staged via global_load_lds, dedicated P buffer -> 1 barrier/tile.
__global__ __launch_bounds__(256) void attn(const u16* __restrict__ Qb, const u16* __restrict__ Kb,
                                            const u16* __restrict__ Vt, u16* __restrict__ Ctx) {
    const int tid  = threadIdx.x;
    const int wv = tid >> 6, lane = tid & 63;
    const int quad = lane >> 4, m16 = lane & 15;
    // load-balanced decode: pair (h, qt) with (h+4, 63-qt) -> co-resident pairs sum to const work
    int bx = blockIdx.x;
    int half = bx >> 8, i0 = bx & 255;
    const int h  = (i0 >> 6) + half * 4;
    const int qt = half ? (63 - (i0 & 63)) : (i0 & 63);
    const int kvh = h >> 1;
    const int q0 = qt * 64;
    const int ntiles = 2 * qt + 2;

    __shared__ __align__(16) u16 Kl[2][32 * 256];   // [buf][kv][d-chunks swizzled]
    __shared__ __align__(16) u16 Vl[2][256 * 32];   // [buf][d][kv-chunks swizzled]
    __shared__ __align__(16) u16 Pl[4][16 * 32];    // wave-private P

    // glds gather maps (choose global chunk per lane so landing order IS the swizzled layout):
    // K: slot s -> (kv=s>>5, c=(s&31)^(kv&7));  V: slot s -> (d=s>>2, cc=(s&3)^(d&3))
    const u16* pK[4]; const u16* pV[4];
    for (int i = 0; i < 4; i++) {
        int s = (wv * 4 + i) * 64 + lane;
        int kv = s >> 5, c = (s & 31) ^ (kv & 7);
        pK[i] = Kb + (size_t)kv * KD + kvh * 256 + c * 8;
        int d = s >> 2, cc = (s & 3) ^ (d & 3);
        pV[i] = Vt + (size_t)(kvh * 256 + d) * S_LEN + cc * 8;
    }
    // Q fragments: 16 rows x 256 d, A-layout
    bf16x8 qf[8];
    {
        const u16* qp = Qb + (size_t)(q0 + wv * 16 + m16) * QD + h * 256 + quad * 8;
        for (int ks = 0; ks < 8; ks++) qf[ks] = *(const bf16x8*)(qp + ks * 32);
    }
    float li[4] = {0.f, 0.f, 0.f, 0.f};
    f32x4 o[16];
    for (int i = 0; i < 16; i++) o[i] = (f32x4){0.f, 0.f, 0.f, 0.f};

    // prologue: stage tile 0 into buf 0
    for (int i = 0; i < 4; i++) {
        glds16(pK[i], &Kl[0][(wv * 4 + i) * 512]);
        glds16(pV[i], &Vl[0][(wv * 4 + i) * 512]);
    }
    __syncthreads();

    for (int kt = 0; kt < ntiles; kt++) {
        const int cur = kt & 1, nxt = cur ^ 1;
        if (kt + 1 < ntiles) {   // async prefetch next tile (overlaps with all compute below)
            size_t koff = (size_t)(kt + 1) * 32 * KD;
            int    voff = (kt + 1) * 32;
            for (int i = 0; i < 4; i++) {
                glds16(pK[i] + koff, &Kl[nxt][(wv * 4 + i) * 512]);
                glds16(pV[i] + voff, &Vl[nxt][(wv * 4 + i) * 512]);
            }
        }
        // S = Q K^T (16 q-rows x 32 kv per wave)
        f32x4 s[2];
        for (int nt = 0; nt < 2; nt++) {
            f32x4 a = (f32x4){0.f, 0.f, 0.f, 0.f};
            int kr = nt * 16 + m16;
            int sw = kr & 7;
            for (int ks = 0; ks < 8; ks++) {
                int c = ks * 4 + quad;
                bf16x8 kf = *(const bf16x8*)(&Kl[cur][kr * 256 + ((c ^ sw) << 3)]);
                a = __builtin_amdgcn_mfma_f32_16x16x32_bf16(qf[ks], kf, a, 0, 0, 0);
            }
            s[nt] = a;
        }
        // softcap -> p = exp(v), mask, accumulate l (no reductions, no rescale)
        const int kvbase = kt * 32;
        for (int nt = 0; nt < 2; nt++)
            for (int r = 0; r < 4; r++) {
                float x2 = s[nt][r] * 0.0025f;              // 2 * (dot*scale)/50
                x2 = fminf(fmaxf(x2, -20.f), 20.f);
                float e = __expf(x2);
                float t = (e - 1.f) * __builtin_amdgcn_rcpf(e + 1.f);
                float p = __expf(50.f * t);
                int kvg = kvbase + nt * 16 + m16;
                int qg  = q0 + wv * 16 + quad * 4 + r;
                p = (kvg > qg) ? 0.f : p;
                li[r] += p;
                s[nt][r] = p;
            }
        // P: C-layout -> LDS (wave-private, no barrier) -> A-layout frag
        u16* Pw = &Pl[wv][0];
        for (int nt = 0; nt < 2; nt++)
            for (int r = 0; r < 4; r++) {
                int m = quad * 4 + r;
                int col = nt * 16 + m16;
                int c = col >> 3, off = col & 7;
                Pw[m * 32 + ((c ^ (m & 3)) << 3) + off] = f2b(s[nt][r]);
            }
        bf16x8 pf = *(const bf16x8*)(&Pw[m16 * 32 + ((quad ^ (m16 & 3)) << 3)]);
        // O += P V
        for (int dt = 0; dt < 16; dt++) {
            int d = dt * 16 + m16;
            bf16x8 vf = *(const bf16x8*)(&Vl[cur][d * 32 + ((quad ^ (d & 3)) << 3)]);
            o[dt] = __builtin_amdgcn_mfma_f32_16x16x32_bf16(pf, vf, o[dt], 0, 0, 0);
        }
        __syncthreads();   // single barrier: cur-buf reads done + nxt-buf glds drained (vmcnt(0))
    }
    // final l reduction across the 16 lanes holding each row, then normalize + store
    float inv[4];
    for (int r = 0; r < 4; r++) {
        float l = li[r];
        l += __shfl_xor(l, 1); l += __shfl_xor(l, 2);
        l += __shfl_xor(l, 4); l += __shfl_xor(l, 8);
        inv[r] = 1.f / l;
    }
    for (int dt = 0; dt < 16; dt++)
        for (int r = 0; r < 4; r++) {
            int row = q0 + wv * 16 + quad * 4 + r;
            int col = dt * 16 + m16;
            Ctx[(size_t)row * QD + h * 256 + col] = f2b(o[dt][r] * inv[r]);
        }
}

// ---------------- launch ----------------
extern "C" void kernel_launch(void* const* d_in, const int* in_sizes, int n_in,
                              void* d_out, int out_size, void* d_ws, size_t ws_size,
                              hipStream_t stream) {
    const float* H  = (const float*)d_in[0];
    const float* Wq = (const float*)d_in[1];
    const float* Wk = (const float*)d_in[2];
    const float* Wv = (const float*)d_in[3];
    const float* Wo = (const float*)d_in[4];
    const int* pos  = (const int*)d_in[5];
    float* out = (float*)d_out;

    char* ws = (char*)d_ws;
    size_t off = 0;
    u16* Hb     = (u16*)(ws + off); off += (size_t)S_LEN * HID * 2;
    u16* Wqkvt  = (u16*)(ws + off); off += (size_t)QKVW * HID * 2;
    u16* Wot    = (u16*)(ws + off); off += (size_t)HID * QD * 2;
    u16* QKVraw = (u16*)(ws + off); off += (size_t)S_LEN * QKVW * 2;
    u16* Qb     = (u16*)(ws + off); off += (size_t)S_LEN * QD * 2;
    u16* Kb     = (u16*)(ws + off); off += (size_t)S_LEN * KD * 2;
    u16* Vt     = (u16*)(ws + off); off += (size_t)KD * S_LEN * 2;
    u16* Ctx    = (u16*)(ws + off); off += (size_t)S_LEN * QD * 2;

    cvt_h<<<dim3((S_LEN * HID / 4 + 255) / 256), dim3(256), 0, stream>>>(H, Hb, S_LEN * HID / 4);
    twcvt<<<dim3(QD / 64, HID / 64), dim3(256), 0, stream>>>(Wq, Wqkvt, HID, QD, HID);
    twcvt<<<dim3(KD / 64, HID / 64), dim3(256), 0, stream>>>(Wk, Wqkvt + (size_t)QD * HID, HID, KD, HID);
    twcvt<<<dim3(KD / 64, HID / 64), dim3(256), 0, stream>>>(Wv, Wqkvt + (size_t)(QD + KD) * HID, HID, KD, HID);
    twcvt<<<dim3(HID / 64, QD / 64), dim3(256), 0, stream>>>(Wo, Wot, QD, HID, QD);
    gemm_bt<1><<<dim3(QKVW / 128, S_LEN / 128), dim3(256), 0, stream>>>(Hb, Wqkvt, QKVraw, S_LEN, QKVW, HID);
    rope_k<<<dim3((S_LEN * NH * 128 + S_LEN * NKV * 128) / 256), dim3(256), 0, stream>>>(QKVraw, pos, Qb, Kb);
    vtrans<<<dim3(S_LEN / 64, KD / 64), dim3(256), 0, stream>>>(QKVraw, Vt);
    attn<<<dim3(512), dim3(256), 0, stream>>>(Qb, Kb, Vt, Ctx);
    gemm_bt<0><<<dim3(HID / 128, S_LEN / 128), dim3(256), 0, stream>>>(Ctx, Wot, out, S_LEN, HID, QD);
}

// Round 5
// 568.191 us; speedup vs baseline: 4.0076x; 1.0087x over previous
//
#include <hip/hip_runtime.h>
#include <cstdint>
#include <cstddef>

typedef unsigned short u16;
typedef short bf16x8 __attribute__((ext_vector_type(8)));
typedef float f32x4 __attribute__((ext_vector_type(4)));

#define S_LEN 4096
#define HID   2304
#define NH    8
#define NKV   4
#define HD    256
#define QD    2048   // NH*HD
#define KD    1024   // NKV*HD
#define QKVW  4096   // QD + KD + KD
#define CHUNK_T 32   // kv-tiles (of 32) per attn block; max 4 chunks at qt=63

__device__ __forceinline__ u16 f2b(float f) {
    union { float f; uint32_t u; } v; v.f = f;
    uint32_t r = (v.u + 0x7FFFu + ((v.u >> 16) & 1u)) >> 16;
    return (u16)r;
}
__device__ __forceinline__ float b2f(u16 u) {
    union { uint32_t u; float f; } v; v.u = ((uint32_t)u) << 16;
    return v.f;
}

// async global->LDS, 16B per lane; LDS dest = wave-uniform base + lane*16
__device__ __forceinline__ void glds16(const void* g, void* l) {
    __builtin_amdgcn_global_load_lds(
        (__attribute__((address_space(1))) void*)(const_cast<void*>(g)),
        (__attribute__((address_space(3))) void*)l, 16, 0, 0);
}

// partial-slot base for (qt): f(qt) = sum_{q<qt} ceil((q+1)/16), closed form
__device__ __forceinline__ int slot_base(int qt) {
    int a = qt >> 4, b = qt & 15;
    return (a + 1) * (8 * a + b);
}
#define SLOTS_PER_HEAD 160   // slot_base(64)

// ---------------- fp32 -> bf16 convert (hidden states) ----------------
__global__ __launch_bounds__(256) void cvt_h(const float* __restrict__ in, u16* __restrict__ out, int n4) {
    int id = blockIdx.x * 256 + threadIdx.x;
    if (id >= n4) return;
    float4 v = ((const float4*)in)[id];
    uint2 o;
    o.x = (uint32_t)f2b(v.x) | ((uint32_t)f2b(v.y) << 16);
    o.y = (uint32_t)f2b(v.z) | ((uint32_t)f2b(v.w) << 16);
    ((uint2*)out)[id] = o;
}

// ---------------- weight transpose+convert: W[K][N] f32 -> out[n][k] bf16 ----------------
__global__ __launch_bounds__(256) void twcvt(const float* __restrict__ W, u16* __restrict__ out,
                                             int K, int N, int ldo) {
    const int n0 = blockIdx.x * 64, k0 = blockIdx.y * 64;
    __shared__ float T[64][68];
    const int t = threadIdx.x;
    for (int i = 0; i < 4; i++) {
        int id = i * 256 + t;
        int r = id >> 4, c4 = id & 15;
        float4 v = *(const float4*)(W + (size_t)(k0 + r) * N + n0 + c4 * 4);
        *(float4*)(&T[r][c4 * 4]) = v;
    }
    __syncthreads();
    for (int i = 0; i < 4; i++) {
        int id = i * 256 + t;
        int rn = id >> 4, c4 = id & 15;
        u16 a = f2b(T[c4 * 4 + 0][rn]);
        u16 b = f2b(T[c4 * 4 + 1][rn]);
        u16 c = f2b(T[c4 * 4 + 2][rn]);
        u16 d = f2b(T[c4 * 4 + 3][rn]);
        uint2 o;
        o.x = (uint32_t)a | ((uint32_t)b << 16);
        o.y = (uint32_t)c | ((uint32_t)d << 16);
        *(uint2*)(out + (size_t)(n0 + rn) * ldo + k0 + c4 * 4) = o;
    }
}

// ---------------- GEMM: C[M][N] = A[M][K] * B[N][K]^T, bf16 in, f32 acc ----------------
// m97 structure: 128x128 tile, BK=32, global_load_lds width-16 staging, XOR-swizzled LDS.
// 16 NAMED accumulators (array form spilled to scratch in R3: VGPR=60, 4.3GB scratch traffic).
template<int BF16_OUT>
__global__ __launch_bounds__(256, 1) void gemm_bt(const u16* __restrict__ A, const u16* __restrict__ B,
                                                  void* __restrict__ Cp, int M, int N, int K) {
    const int tid  = threadIdx.x;
    const int wv = tid >> 6, lane = tid & 63;
    const int quad = lane >> 4, m16 = lane & 15;
    const int m0 = blockIdx.y * 128, n0 = blockIdx.x * 128;
    const int wm = (wv & 1) * 64, wn = (wv >> 1) * 64;
    __shared__ __align__(16) u16 As[128 * 32];
    __shared__ __align__(16) u16 Bs[128 * 32];
    int s0i = (wv * 2) * 64 + lane, s1i = s0i + 64;
    int row0 = s0i >> 2, c0 = (s0i & 3) ^ (row0 & 3);
    int row1 = s1i >> 2, c1 = (s1i & 3) ^ (row1 & 3);
    const u16* pA0 = A + (size_t)(m0 + row0) * K + c0 * 8;
    const u16* pA1 = A + (size_t)(m0 + row1) * K + c1 * 8;
    const u16* pB0 = B + (size_t)(n0 + row0) * K + c0 * 8;
    const u16* pB1 = B + (size_t)(n0 + row1) * K + c1 * 8;
    u16* lA0 = &As[(wv * 2 + 0) * 512]; u16* lA1 = &As[(wv * 2 + 1) * 512];
    u16* lB0 = &Bs[(wv * 2 + 0) * 512]; u16* lB1 = &Bs[(wv * 2 + 1) * 512];

    const f32x4 z4 = {0.f, 0.f, 0.f, 0.f};
    f32x4 acc00 = z4, acc01 = z4, acc02 = z4, acc03 = z4;
    f32x4 acc10 = z4, acc11 = z4, acc12 = z4, acc13 = z4;
    f32x4 acc20 = z4, acc21 = z4, acc22 = z4, acc23 = z4;
    f32x4 acc30 = z4, acc31 = z4, acc32 = z4, acc33 = z4;

    const int sw = quad ^ (m16 & 3);
    const u16* ra0 = &As[(wm + 0 * 16 + m16) * 32 + (sw << 3)];
    const u16* ra1 = &As[(wm + 1 * 16 + m16) * 32 + (sw << 3)];
    const u16* ra2 = &As[(wm + 2 * 16 + m16) * 32 + (sw << 3)];
    const u16* ra3 = &As[(wm + 3 * 16 + m16) * 32 + (sw << 3)];
    const u16* rb0 = &Bs[(wn + 0 * 16 + m16) * 32 + (sw << 3)];
    const u16* rb1 = &Bs[(wn + 1 * 16 + m16) * 32 + (sw << 3)];
    const u16* rb2 = &Bs[(wn + 2 * 16 + m16) * 32 + (sw << 3)];
    const u16* rb3 = &Bs[(wn + 3 * 16 + m16) * 32 + (sw << 3)];

    for (int k0 = 0; k0 < K; k0 += 32) {
        __syncthreads();
        glds16(pA0 + k0, lA0);
        glds16(pA1 + k0, lA1);
        glds16(pB0 + k0, lB0);
        glds16(pB1 + k0, lB1);
        __syncthreads();
        bf16x8 af0 = *(const bf16x8*)ra0, af1 = *(const bf16x8*)ra1;
        bf16x8 af2 = *(const bf16x8*)ra2, af3 = *(const bf16x8*)ra3;
        bf16x8 bf0 = *(const bf16x8*)rb0, bf1 = *(const bf16x8*)rb1;
        bf16x8 bf2 = *(const bf16x8*)rb2, bf3 = *(const bf16x8*)rb3;
        acc00 = __builtin_amdgcn_mfma_f32_16x16x32_bf16(af0, bf0, acc00, 0, 0, 0);
        acc01 = __builtin_amdgcn_mfma_f32_16x16x32_bf16(af0, bf1, acc01, 0, 0, 0);
        acc02 = __builtin_amdgcn_mfma_f32_16x16x32_bf16(af0, bf2, acc02, 0, 0, 0);
        acc03 = __builtin_amdgcn_mfma_f32_16x16x32_bf16(af0, bf3, acc03, 0, 0, 0);
        acc10 = __builtin_amdgcn_mfma_f32_16x16x32_bf16(af1, bf0, acc10, 0, 0, 0);
        acc11 = __builtin_amdgcn_mfma_f32_16x16x32_bf16(af1, bf1, acc11, 0, 0, 0);
        acc12 = __builtin_amdgcn_mfma_f32_16x16x32_bf16(af1, bf2, acc12, 0, 0, 0);
        acc13 = __builtin_amdgcn_mfma_f32_16x16x32_bf16(af1, bf3, acc13, 0, 0, 0);
        acc20 = __builtin_amdgcn_mfma_f32_16x16x32_bf16(af2, bf0, acc20, 0, 0, 0);
        acc21 = __builtin_amdgcn_mfma_f32_16x16x32_bf16(af2, bf1, acc21, 0, 0, 0);
        acc22 = __builtin_amdgcn_mfma_f32_16x16x32_bf16(af2, bf2, acc22, 0, 0, 0);
        acc23 = __builtin_amdgcn_mfma_f32_16x16x32_bf16(af2, bf3, acc23, 0, 0, 0);
        acc30 = __builtin_amdgcn_mfma_f32_16x16x32_bf16(af3, bf0, acc30, 0, 0, 0);
        acc31 = __builtin_amdgcn_mfma_f32_16x16x32_bf16(af3, bf1, acc31, 0, 0, 0);
        acc32 = __builtin_amdgcn_mfma_f32_16x16x32_bf16(af3, bf2, acc32, 0, 0, 0);
        acc33 = __builtin_amdgcn_mfma_f32_16x16x32_bf16(af3, bf3, acc33, 0, 0, 0);
    }

#define STORE_TILE(I, J, ACC)                                              \
    {                                                                      \
        _Pragma("unroll")                                                  \
        for (int r = 0; r < 4; r++) {                                      \
            int row = m0 + wm + (I) * 16 + quad * 4 + r;                   \
            int col = n0 + wn + (J) * 16 + m16;                            \
            float v = (ACC)[r];                                            \
            if (BF16_OUT) ((u16*)Cp)[(size_t)row * N + col] = f2b(v);      \
            else          ((float*)Cp)[(size_t)row * N + col] = v;         \
        }                                                                  \
    }
    STORE_TILE(0, 0, acc00) STORE_TILE(0, 1, acc01) STORE_TILE(0, 2, acc02) STORE_TILE(0, 3, acc03)
    STORE_TILE(1, 0, acc10) STORE_TILE(1, 1, acc11) STORE_TILE(1, 2, acc12) STORE_TILE(1, 3, acc13)
    STORE_TILE(2, 0, acc20) STORE_TILE(2, 1, acc21) STORE_TILE(2, 2, acc22) STORE_TILE(2, 3, acc23)
    STORE_TILE(3, 0, acc30) STORE_TILE(3, 1, acc31) STORE_TILE(3, 2, acc32) STORE_TILE(3, 3, acc33)
#undef STORE_TILE
}

// ---------------- RoPE (Q and K), bf16 in/out ----------------
__global__ __launch_bounds__(256) void rope_k(const u16* __restrict__ QKV, const int* __restrict__ pos,
                                              u16* __restrict__ Qb, u16* __restrict__ Kb) {
    int id = blockIdx.x * 256 + threadIdx.x;
    const int NQ = S_LEN * NH * 128;
    const u16* src; u16* dst;
    int s, j;
    if (id < NQ) {
        s = id >> 10; int rem = id & 1023; int h = rem >> 7; j = rem & 127;
        src = QKV + (size_t)s * QKVW + h * 256;
        dst = Qb + (size_t)s * QD + h * 256;
    } else {
        int id2 = id - NQ;
        s = id2 >> 9; int rem = id2 & 511; int kvh = rem >> 7; j = rem & 127;
        src = QKV + (size_t)s * QKVW + QD + kvh * 256;
        dst = Kb + (size_t)s * KD + kvh * 256;
    }
    float p = (float)pos[s];
    float invf = expf(-0.07195578429985445f * (float)j);
    float ang = p * invf;
    float sn, cs;
    sincosf(ang, &sn, &cs);
    float x1 = b2f(src[j]), x2 = b2f(src[j + 128]);
    dst[j]       = f2b(x1 * cs - x2 * sn);
    dst[j + 128] = f2b(x2 * cs + x1 * sn);
}

// ---------------- V transpose: QKV[:, 3072+d] -> Vt[d][s] (bf16) ----------------
__global__ __launch_bounds__(256) void vtrans(const u16* __restrict__ QKV, u16* __restrict__ Vt) {
    const int s0 = blockIdx.x * 64, d0 = blockIdx.y * 64;
    __shared__ u16 T[64][72];
    const int t = threadIdx.x;
    for (int i = 0; i < 2; i++) {
        int id = i * 256 + t;
        int r = id >> 3, c = id & 7;
        uint4 v = *(const uint4*)(QKV + (size_t)(s0 + r) * QKVW + (QD + KD) + d0 + c * 8);
        *(uint4*)(&T[r][c * 8]) = v;
    }
    __syncthreads();
    for (int i = 0; i < 2; i++) {
        int id = i * 256 + t;
        int r = id >> 3, c = id & 7;
        union { u16 u[8]; uint4 v; } o;
        for (int jj = 0; jj < 8; jj++) o.u[jj] = T[c * 8 + jj][r];
        *(uint4*)(Vt + (size_t)(d0 + r) * S_LEN + s0 + c * 8) = o.v;
    }
}

// ---------------- flash attention partials: kv-split (flash-decoding) ----------------
// Fixed-max softmax (softcap bounds scores to [-50,50]) makes partials ADDITIVE across any
// kv partition: each block handles <=32 kv-tiles of one (h, qt) and writes unnormalized
// f32 O-partial + l-partial. Uniform block size kills the R4 tail (2..128-tile blocks).
__global__ __launch_bounds__(256) void attn_part(const u16* __restrict__ Qb, const u16* __restrict__ Kb,
                                                 const u16* __restrict__ Vt,
                                                 float* __restrict__ Part, float* __restrict__ Lpart) {
    const int tid  = threadIdx.x;
    const int wv = tid >> 6, lane = tid & 63;
    const int quad = lane >> 4, m16 = lane & 15;
    const int qt = blockIdx.x, h = blockIdx.y, ch = blockIdx.z;
    const int n_kvt = 2 * qt + 2;
    const int t0 = ch * CHUNK_T;
    if (t0 >= n_kvt) return;
    const int t1 = min(t0 + CHUNK_T, n_kvt);
    const int kvh = h >> 1;
    const int q0 = qt * 64;
    const int slot = h * SLOTS_PER_HEAD + slot_base(qt) + ch;

    __shared__ __align__(16) u16 Kl[2][32 * 256];
    __shared__ __align__(16) u16 Vl[2][256 * 32];
    __shared__ __align__(16) u16 Pl[4][16 * 32];

    // glds gather maps: lane landing order IS the swizzled layout
    const u16* pK[4]; const u16* pV[4];
    for (int i = 0; i < 4; i++) {
        int s = (wv * 4 + i) * 64 + lane;
        int kv = s >> 5, c = (s & 31) ^ (kv & 7);
        pK[i] = Kb + (size_t)kv * KD + kvh * 256 + c * 8;
        int d = s >> 2, cc = (s & 3) ^ (d & 3);
        pV[i] = Vt + (size_t)(kvh * 256 + d) * S_LEN + cc * 8;
    }
    // Q fragments: 16 rows x 256 d, A-layout
    bf16x8 qf[8];
    {
        const u16* qp = Qb + (size_t)(q0 + wv * 16 + m16) * QD + h * 256 + quad * 8;
        for (int ks = 0; ks < 8; ks++) qf[ks] = *(const bf16x8*)(qp + ks * 32);
    }
    float li[4] = {0.f, 0.f, 0.f, 0.f};
    f32x4 o[16];
    for (int i = 0; i < 16; i++) o[i] = (f32x4){0.f, 0.f, 0.f, 0.f};

    // prologue: stage tile t0 into buf 0
    {
        size_t koff = (size_t)t0 * 32 * KD;
        int    voff = t0 * 32;
        for (int i = 0; i < 4; i++) {
            glds16(pK[i] + koff, &Kl[0][(wv * 4 + i) * 512]);
            glds16(pV[i] + voff, &Vl[0][(wv * 4 + i) * 512]);
        }
    }
    __syncthreads();

    for (int kt = t0; kt < t1; kt++) {
        const int cur = (kt - t0) & 1, nxt = cur ^ 1;
        if (kt + 1 < t1) {
            size_t koff = (size_t)(kt + 1) * 32 * KD;
            int    voff = (kt + 1) * 32;
            for (int i = 0; i < 4; i++) {
                glds16(pK[i] + koff, &Kl[nxt][(wv * 4 + i) * 512]);
                glds16(pV[i] + voff, &Vl[nxt][(wv * 4 + i) * 512]);
            }
        }
        // S = Q K^T
        f32x4 s[2];
        for (int nt = 0; nt < 2; nt++) {
            f32x4 a = (f32x4){0.f, 0.f, 0.f, 0.f};
            int kr = nt * 16 + m16;
            int sw = kr & 7;
            for (int ks = 0; ks < 8; ks++) {
                int c = ks * 4 + quad;
                bf16x8 kf = *(const bf16x8*)(&Kl[cur][kr * 256 + ((c ^ sw) << 3)]);
                a = __builtin_amdgcn_mfma_f32_16x16x32_bf16(qf[ks], kf, a, 0, 0, 0);
            }
            s[nt] = a;
        }
        // softcap -> p = exp(v), causal mask, accumulate l
        const int kvbase = kt * 32;
        for (int nt = 0; nt < 2; nt++)
            for (int r = 0; r < 4; r++) {
                float x2 = s[nt][r] * 0.0025f;
                x2 = fminf(fmaxf(x2, -20.f), 20.f);
                float e = __expf(x2);
                float t = (e - 1.f) * __builtin_amdgcn_rcpf(e + 1.f);
                float p = __expf(50.f * t);
                int kvg = kvbase + nt * 16 + m16;
                int qg  = q0 + wv * 16 + quad * 4 + r;
                p = (kvg > qg) ? 0.f : p;
                li[r] += p;
                s[nt][r] = p;
            }
        // P: C-layout -> wave-private LDS -> A-layout frag
        u16* Pw = &Pl[wv][0];
        for (int nt = 0; nt < 2; nt++)
            for (int r = 0; r < 4; r++) {
                int m = quad * 4 + r;
                int col = nt * 16 + m16;
                int c = col >> 3, off = col & 7;
                Pw[m * 32 + ((c ^ (m & 3)) << 3) + off] = f2b(s[nt][r]);
            }
        bf16x8 pf = *(const bf16x8*)(&Pw[m16 * 32 + ((quad ^ (m16 & 3)) << 3)]);
        // O += P V
        for (int dt = 0; dt < 16; dt++) {
            int d = dt * 16 + m16;
            bf16x8 vf = *(const bf16x8*)(&Vl[cur][d * 32 + ((quad ^ (d & 3)) << 3)]);
            o[dt] = __builtin_amdgcn_mfma_f32_16x16x32_bf16(pf, vf, o[dt], 0, 0, 0);
        }
        __syncthreads();
    }
    // write partials: O (unnormalized f32 [64][256]) and l (f32 [64])
    float* Pp = Part + (size_t)slot * (64 * 256);
    for (int dt = 0; dt < 16; dt++)
        for (int r = 0; r < 4; r++)
            Pp[(wv * 16 + quad * 4 + r) * 256 + dt * 16 + m16] = o[dt][r];
    for (int r = 0; r < 4; r++) {
        float l = li[r];
        l += __shfl_xor(l, 1); l += __shfl_xor(l, 2);
        l += __shfl_xor(l, 4); l += __shfl_xor(l, 8);
        if (m16 == 0) Lpart[slot * 64 + wv * 16 + quad * 4 + r] = l;
    }
}

// ---------------- combine partials + normalize -> Ctx bf16 ----------------
__global__ __launch_bounds__(256) void attn_combine(const float* __restrict__ Part,
                                                    const float* __restrict__ Lpart,
                                                    u16* __restrict__ Ctx) {
    const int qt = blockIdx.x & 63, h = blockIdx.x >> 6;
    const int nch = (qt >> 4) + 1;
    const int slot0 = h * SLOTS_PER_HEAD + slot_base(qt);
    const int t = threadIdx.x;
    const int q0 = qt * 64;
    __shared__ float linv[64];
    if (t < 64) {
        float l = 0.f;
        for (int c = 0; c < nch; c++) l += Lpart[(slot0 + c) * 64 + t];
        linv[t] = 1.f / l;
    }
    __syncthreads();
    const float* P0 = Part + (size_t)slot0 * (64 * 256);
    for (int i = 0; i < 16; i++) {
        int f4 = i * 256 + t;           // float4 index over [64][64]
        int row = f4 >> 6, c4 = f4 & 63;
        float4 a = *(const float4*)(P0 + row * 256 + c4 * 4);
        for (int c = 1; c < nch; c++) {
            float4 b = *(const float4*)(P0 + (size_t)c * (64 * 256) + row * 256 + c4 * 4);
            a.x += b.x; a.y += b.y; a.z += b.z; a.w += b.w;
        }
        float iv = linv[row];
        uint2 ov;
        ov.x = (uint32_t)f2b(a.x * iv) | ((uint32_t)f2b(a.y * iv) << 16);
        ov.y = (uint32_t)f2b(a.z * iv) | ((uint32_t)f2b(a.w * iv) << 16);
        *(uint2*)(Ctx + (size_t)(q0 + row) * QD + h * 256 + c4 * 4) = ov;
    }
}

// ---------------- launch ----------------
extern "C" void kernel_launch(void* const* d_in, const int* in_sizes, int n_in,
                              void* d_out, int out_size, void* d_ws, size_t ws_size,
                              hipStream_t stream) {
    const float* H  = (const float*)d_in[0];
    const float* Wq = (const float*)d_in[1];
    const float* Wk = (const float*)d_in[2];
    const float* Wv = (const float*)d_in[3];
    const float* Wo = (const float*)d_in[4];
    const int* pos  = (const int*)d_in[5];
    float* out = (float*)d_out;

    char* ws = (char*)d_ws;
    size_t off = 0;
    u16* Hb     = (u16*)(ws + off); off += (size_t)S_LEN * HID * 2;
    u16* Wqkvt  = (u16*)(ws + off); off += (size_t)QKVW * HID * 2;
    u16* Wot    = (u16*)(ws + off); off += (size_t)HID * QD * 2;
    u16* QKVraw = (u16*)(ws + off); off += (size_t)S_LEN * QKVW * 2;
    u16* Qb     = (u16*)(ws + off); off += (size_t)S_LEN * QD * 2;
    u16* Kb     = (u16*)(ws + off); off += (size_t)S_LEN * KD * 2;
    u16* Vt     = (u16*)(ws + off); off += (size_t)KD * S_LEN * 2;
    u16* Ctx    = (u16*)(ws + off); off += (size_t)S_LEN * QD * 2;
    float* Part = (float*)(ws + off); off += (size_t)NH * SLOTS_PER_HEAD * 64 * 256 * 4;  // 83.9MB
    float* Lprt = (float*)(ws + off); off += (size_t)NH * SLOTS_PER_HEAD * 64 * 4;        // 0.33MB

    cvt_h<<<dim3((S_LEN * HID / 4 + 255) / 256), dim3(256), 0, stream>>>(H, Hb, S_LEN * HID / 4);
    twcvt<<<dim3(QD / 64, HID / 64), dim3(256), 0, stream>>>(Wq, Wqkvt, HID, QD, HID);
    twcvt<<<dim3(KD / 64, HID / 64), dim3(256), 0, stream>>>(Wk, Wqkvt + (size_t)QD * HID, HID, KD, HID);
    twcvt<<<dim3(KD / 64, HID / 64), dim3(256), 0, stream>>>(Wv, Wqkvt + (size_t)(QD + KD) * HID, HID, KD, HID);
    twcvt<<<dim3(HID / 64, QD / 64), dim3(256), 0, stream>>>(Wo, Wot, QD, HID, QD);
    gemm_bt<1><<<dim3(QKVW / 128, S_LEN / 128), dim3(256), 0, stream>>>(Hb, Wqkvt, QKVraw, S_LEN, QKVW, HID);
    rope_k<<<dim3((S_LEN * NH * 128 + S_LEN * NKV * 128) / 256), dim3(256), 0, stream>>>(QKVraw, pos, Qb, Kb);
    vtrans<<<dim3(S_LEN / 64, KD / 64), dim3(256), 0, stream>>>(QKVraw, Vt);
    attn_part<<<dim3(64, NH, 4), dim3(256), 0, stream>>>(Qb, Kb, Vt, Part, Lprt);
    attn_combine<<<dim3(512), dim3(256), 0, stream>>>(Part, Lprt, Ctx);
    gemm_bt<0><<<dim3(HID / 128, S_LEN / 128), dim3(256), 0, stream>>>(Ctx, Wot, out, S_LEN, HID, QD);
}